// Round 14
// baseline (23.246 us; speedup 1.0000x reference)
//
#include <hip/hip_runtime.h>
#include <hip/hip_bf16.h>
#include <math.h>

// TTMultiheadAttention via MFMA (round 13 = round 12 wave-program, 4 units/block):
//   per s:  G_i[e,d] = sum_q brs_i[e,q] * x[q,s,d]      (mfma 32x32x16 bf16)
//           P_i = exp2(G_i)   (brs pre-scaled by cA2_i*log2e/sqrt(32))
//           OUT_i[b,d] = sum_e CrT_sigma[b,e] * P_i[e,d] (mfma, row 16 = ones -> l_i)
//           out[b,s,d] = sum_i OUT_i[b,d] / l_i[d]
// Round-13 change (census: compute ~9us @ ~88% VALU-busy; in-kernel fixed ~12us
// is the dominant, VALU-idle term; all its candidates -- dispatch ramp, 40MB
// cross-XCD weight re-fetch, cold I-cache, stage drain -- scale with BLOCK
// COUNT): grid 256 (1 block/CU), 512 threads = 8 waves; waves 0-3 own dhalf 0,
// waves 4-7 own dhalf 1; each block loops over 2 consecutive s. One staging of
// 40KB serves 4 units (was 1). LDS is read-only after the single barrier, so
// the two s-rounds need NO further barriers (waves drift freely). Both rounds'
// x fragments prefetched before the barrier. Unit wave-program = r12 exactly.

#define SS 512
#define DD 256
#define R2 16
#define NI 3

#define BR_UNITS (NI * 8 * 64)              // 1536 x 16B
#define CR_UNITS (16 * 64)                  // 1024 x 16B
#define ALL_UNITS (BR_UNITS + CR_UNITS)     // 2560 x 16B = 40 KB
#define BR_USH (BR_UNITS * 8)               // 12288 ushorts
#define WS_USH (ALL_UNITS * 8)              // 20480 ushorts

typedef __attribute__((ext_vector_type(8))) short bf16x8;
typedef __attribute__((ext_vector_type(8))) unsigned short ushort8;
typedef __attribute__((ext_vector_type(16))) float f32x16;
typedef __attribute__((ext_vector_type(2))) unsigned uint2v;

union B8 { unsigned w[4]; bf16x8 v; };

static __device__ __forceinline__ unsigned short bf16bits(float f) {
    union { __hip_bfloat16 h; unsigned short u; } c;
    c.h = __float2bfloat16(f);
    return c.u;
}
static __device__ __forceinline__ unsigned packb(float a, float b) {
    union { __hip_bfloat162 h; unsigned u; } c;
    c.h = __float22bfloat162_rn(make_float2(a, b));
    return c.u;
}
// ONE-instruction pack: dst = {b[31:16], a[31:16]} = {bf16_trunc(b), bf16_trunc(a)}
static __device__ __forceinline__ unsigned permpack(float a, float b) {
    union { float f; unsigned u; } ua, ub;
    ua.f = a; ub.f = b;
    return __builtin_amdgcn_perm(ub.u, ua.u, 0x07060302u);
}

// Fragment packing (one b128 store per thread, 2560 threads = grid 10 x 256):
// brf[((i*8+et)*64 + l)*8 + j] = bf16(br[i][et*32+(l&31)][8*(l>>5)+j] * cA2_i)
// crf: k-slot-permuted CrT (+ ones row at b==16):
//   e = et*32 + h*16 + (j&3) + 8*(j>>2) + 4*(l>>5)     <-- sigma(k-slot)
__global__ void tt_prep(const float* __restrict__ ar,
                        const float* __restrict__ br,
                        const float* __restrict__ cr,
                        unsigned short* __restrict__ wsf)
{
    const int t = blockIdx.x * 256 + threadIdx.x;   // 0..2559
    float cA2[NI];
#pragma unroll
    for (int i = 0; i < NI; ++i) {
        float A = ar[0 * NI + i] + ar[1 * NI + i] + ar[2 * NI + i];
        cA2[i] = A * (0.17677669529663687f * 1.4426950408889634f);
    }
    if (t < BR_UNITS) {
        const int l = t & 63, et = (t >> 6) & 7, i = t >> 9;
        const float* src = br + (i * DD + et * 32 + (l & 31)) * R2 + 8 * (l >> 5);
        const float sc = cA2[i];
        ushort8 v;
#pragma unroll
        for (int j = 0; j < 8; ++j) v[j] = bf16bits(src[j] * sc);
        *(ushort8*)(wsf + t * 8) = v;
    } else {
        const int idx = t - BR_UNITS;               // 0..1023
        const int l = idx & 63, h = (idx >> 6) & 1, et = idx >> 7;
        const int b = l & 31;
        ushort8 v;
#pragma unroll
        for (int j = 0; j < 8; ++j) {
            const int e = et * 32 + h * 16 + (j & 3) + 8 * (j >> 2) + 4 * (l >> 5);
            float val = (b < 16) ? cr[b * DD + e] : (b == 16 ? 1.0f : 0.0f);
            v[j] = bf16bits(val);
        }
        *(ushort8*)(wsf + (BR_USH + idx * 8)) = v;
    }
}

__global__ __launch_bounds__(512, 2) void tt_attn_mfma(
    const float* __restrict__ x,
    const unsigned short* __restrict__ wsf,
    float* __restrict__ out)
{
    __shared__ unsigned short lds[WS_USH];          // 40960 B

    const int tid  = threadIdx.x;                   // 0..511
    const int lane = tid & 63;
    const int wv   = tid >> 6;                      // 0..7
    const int hi   = lane >> 5;
    const int d    = (wv >> 2) * 128 + (wv & 3) * 32 + (lane & 31);  // 0..255
    const int s0   = blockIdx.x * 2;                // this block: s0, s0+1

    // Stage all weight fragments to LDS: 5 chunks x 512 threads x 16 B = 40 KB.
#pragma unroll
    for (int c = 0; c < 5; ++c) {
        const char* g = (const char*)wsf + (size_t)(c * 512 + tid) * 16;
        char* lp = (char*)lds + (size_t)(c * 512 + wv * 64) * 16;
        __builtin_amdgcn_global_load_lds(
            (const __attribute__((address_space(1))) void*)g,
            (__attribute__((address_space(3))) void*)lp, 16, 0, 0);
    }

    // Prefetch BOTH rounds' x fragments while staging is in flight.
    // lane holds x[q = 8*hi + j][s][d]  (B-operand of stage 1)
    const float* xp = x + s0 * DD + d + (hi ? 8 * SS * DD : 0);
    float xr0[8], xr1[8];
#pragma unroll
    for (int t = 0; t < 8; ++t) { xr0[t] = xp[t * SS * DD]; xr1[t] = xp[t * SS * DD + DD]; }
    B8 xb0, xb1;
#pragma unroll
    for (int t = 0; t < 4; ++t) {
        xb0.w[t] = packb(xr0[2 * t], xr0[2 * t + 1]);   // RNE (once per x value)
        xb1.w[t] = packb(xr1[2 * t], xr1[2 * t + 1]);
    }

    __syncthreads();   // drains vmcnt; LDS is READ-ONLY afterwards (no more barriers)

    const unsigned short* brl = lds + lane * 8;
    const unsigned short* crl = lds + BR_USH + lane * 8;
    const f32x16 zf{};

#pragma unroll 1
    for (int r = 0; r < 2; ++r) {
        B8 xsel;
#pragma unroll
        for (int t = 0; t < 4; ++t) xsel.w[t] = r ? xb1.w[t] : xb0.w[t];
        const bf16x8 xf = xsel.v;

        f32x16 acc0{}, acc1{}, acc2{};

#pragma unroll 2
        for (int et = 0; et < 8; ++et) {
            const bf16x8 crA0 = *(const bf16x8*)(crl + (et * 2 + 0) * 512);
            const bf16x8 crA1 = *(const bf16x8*)(crl + (et * 2 + 1) * 512);
#pragma unroll
            for (int i = 0; i < NI; ++i) {
                const bf16x8 brA = *(const bf16x8*)(brl + (i * 8 + et) * 512);
                f32x16 g = __builtin_amdgcn_mfma_f32_32x32x16_bf16(brA, xf, zf, 0, 0, 0);
                float p[16];
#pragma unroll
                for (int rr = 0; rr < 16; ++rr) p[rr] = __builtin_amdgcn_exp2f(g[rr]);
                // packs feed stage-2 B operand DIRECTLY (k-slots sigma-permuted on A side)
                B8 P0, P1;
                P0.w[0] = permpack(p[0],  p[1]);
                P0.w[1] = permpack(p[2],  p[3]);
                P0.w[2] = permpack(p[4],  p[5]);
                P0.w[3] = permpack(p[6],  p[7]);
                P1.w[0] = permpack(p[8],  p[9]);
                P1.w[1] = permpack(p[10], p[11]);
                P1.w[2] = permpack(p[12], p[13]);
                P1.w[3] = permpack(p[14], p[15]);
                if (i == 0) {
                    acc0 = __builtin_amdgcn_mfma_f32_32x32x16_bf16(crA0, P0.v, acc0, 0, 0, 0);
                    acc0 = __builtin_amdgcn_mfma_f32_32x32x16_bf16(crA1, P1.v, acc0, 0, 0, 0);
                } else if (i == 1) {
                    acc1 = __builtin_amdgcn_mfma_f32_32x32x16_bf16(crA0, P0.v, acc1, 0, 0, 0);
                    acc1 = __builtin_amdgcn_mfma_f32_32x32x16_bf16(crA1, P1.v, acc1, 0, 0, 0);
                } else {
                    acc2 = __builtin_amdgcn_mfma_f32_32x32x16_bf16(crA0, P0.v, acc2, 0, 0, 0);
                    acc2 = __builtin_amdgcn_mfma_f32_32x32x16_bf16(crA1, P1.v, acc2, 0, 0, 0);
                }
            }
        }

        // l_i sits in C row 16 = reg 8 of hi=0 lanes; broadcast to hi=1 half
        float inv[NI];
#pragma unroll
        for (int i = 0; i < NI; ++i) {
            union { float f; unsigned u; } c;
            c.f = (i == 0) ? acc0[8] : (i == 1) ? acc1[8] : acc2[8];
            const uint2v rr = __builtin_amdgcn_permlane32_swap(c.u, c.u, false, false);
            union { unsigned u; float f; } c2; c2.u = rr.x;
            inv[i] = 1.0f / c2.f;
        }

        const int s = s0 + r;
#pragma unroll
        for (int rr = 0; rr < 8; ++rr) {
            const int b = (rr & 3) + 8 * (rr >> 2) + 4 * hi;
            const float o = acc0[rr] * inv[0] + acc1[rr] * inv[1] + acc2[rr] * inv[2];
            out[(b * SS + s) * DD + d] = o;
        }
    }
}

extern "C" void kernel_launch(void* const* d_in, const int* in_sizes, int n_in,
                              void* d_out, int out_size, void* d_ws, size_t ws_size,
                              hipStream_t stream) {
    const float* x  = (const float*)d_in[0];
    const float* ar = (const float*)d_in[1];
    const float* br = (const float*)d_in[2];
    const float* cr = (const float*)d_in[3];
    float* out = (float*)d_out;

    unsigned short* wsf = (unsigned short*)d_ws;   // 40 KB: brf (24K) then crf (16K)

    hipLaunchKernelGGL(tt_prep, dim3(10), dim3(256), 0, stream, ar, br, cr, wsf);
    hipLaunchKernelGGL(tt_attn_mfma, dim3(SS / 2), dim3(512), 0, stream, x, wsf, out);
}

// Round 15
// 23.201 us; speedup vs baseline: 1.0020x; 1.0020x over previous
//
#include <hip/hip_runtime.h>
#include <hip/hip_bf16.h>
#include <math.h>

// TTMultiheadAttention via MFMA (round 14 = round 12 + 2-s interleaved streams):
//   per s:  G_i[e,d] = sum_q brs_i[e,q] * x[q,s,d]      (mfma 32x32x16 bf16)
//           P_i = exp2(G_i)   (brs pre-scaled by cA2_i*log2e/sqrt(32))
//           OUT_i[b,d] = sum_e CrT_sigma[b,e] * P_i[e,d] (mfma, row 16 = ones -> l_i)
//           out[b,s,d] = sum_i OUT_i[b,d] / l_i[d]
// Round-14 change (r13 falsified per-block fixed cost; census shows ~1/3 of
// compute is dependency stalls at the LDS/VGPR-pinned 2 blocks/CU): each wave
// now carries TWO independent s-streams interleaved through the (et,i) body,
// sharing one ds_read of brA/crA. At every dependency stall the scheduler has
// a ready instr from the sibling stream. VGPR ~170 is free (launch_bounds
// (256,2): occupancy is LDS-capped at 2 blocks/CU regardless). Per-s math is
// byte-identical to r12. Grid halves to 512 blocks.

#define SS 512
#define DD 256
#define R2 16
#define NI 3

#define BR_UNITS (NI * 8 * 64)              // 1536 x 16B
#define CR_UNITS (16 * 64)                  // 1024 x 16B
#define ALL_UNITS (BR_UNITS + CR_UNITS)     // 2560 x 16B = 40 KB
#define BR_USH (BR_UNITS * 8)               // 12288 ushorts
#define WS_USH (ALL_UNITS * 8)              // 20480 ushorts

typedef __attribute__((ext_vector_type(8))) short bf16x8;
typedef __attribute__((ext_vector_type(8))) unsigned short ushort8;
typedef __attribute__((ext_vector_type(16))) float f32x16;
typedef __attribute__((ext_vector_type(2))) unsigned uint2v;

union B8 { unsigned w[4]; bf16x8 v; };

static __device__ __forceinline__ unsigned short bf16bits(float f) {
    union { __hip_bfloat16 h; unsigned short u; } c;
    c.h = __float2bfloat16(f);
    return c.u;
}
static __device__ __forceinline__ unsigned packb(float a, float b) {
    union { __hip_bfloat162 h; unsigned u; } c;
    c.h = __float22bfloat162_rn(make_float2(a, b));
    return c.u;
}
// ONE-instruction pack: dst = {b[31:16], a[31:16]} = {bf16_trunc(b), bf16_trunc(a)}
static __device__ __forceinline__ unsigned permpack(float a, float b) {
    union { float f; unsigned u; } ua, ub;
    ua.f = a; ub.f = b;
    return __builtin_amdgcn_perm(ub.u, ua.u, 0x07060302u);
}

// Fragment packing (one b128 store per thread, 2560 threads = grid 10 x 256):
// brf[((i*8+et)*64 + l)*8 + j] = bf16(br[i][et*32+(l&31)][8*(l>>5)+j] * cA2_i)
// crf: k-slot-permuted CrT (+ ones row at b==16):
//   e = et*32 + h*16 + (j&3) + 8*(j>>2) + 4*(l>>5)     <-- sigma(k-slot)
__global__ void tt_prep(const float* __restrict__ ar,
                        const float* __restrict__ br,
                        const float* __restrict__ cr,
                        unsigned short* __restrict__ wsf)
{
    const int t = blockIdx.x * 256 + threadIdx.x;   // 0..2559
    float cA2[NI];
#pragma unroll
    for (int i = 0; i < NI; ++i) {
        float A = ar[0 * NI + i] + ar[1 * NI + i] + ar[2 * NI + i];
        cA2[i] = A * (0.17677669529663687f * 1.4426950408889634f);
    }
    if (t < BR_UNITS) {
        const int l = t & 63, et = (t >> 6) & 7, i = t >> 9;
        const float* src = br + (i * DD + et * 32 + (l & 31)) * R2 + 8 * (l >> 5);
        const float sc = cA2[i];
        ushort8 v;
#pragma unroll
        for (int j = 0; j < 8; ++j) v[j] = bf16bits(src[j] * sc);
        *(ushort8*)(wsf + t * 8) = v;
    } else {
        const int idx = t - BR_UNITS;               // 0..1023
        const int l = idx & 63, h = (idx >> 6) & 1, et = idx >> 7;
        const int b = l & 31;
        ushort8 v;
#pragma unroll
        for (int j = 0; j < 8; ++j) {
            const int e = et * 32 + h * 16 + (j & 3) + 8 * (j >> 2) + 4 * (l >> 5);
            float val = (b < 16) ? cr[b * DD + e] : (b == 16 ? 1.0f : 0.0f);
            v[j] = bf16bits(val);
        }
        *(ushort8*)(wsf + (BR_USH + idx * 8)) = v;
    }
}

__global__ __launch_bounds__(256, 2) void tt_attn_mfma(
    const float* __restrict__ x,
    const unsigned short* __restrict__ wsf,
    float* __restrict__ out)
{
    __shared__ unsigned short lds[WS_USH];          // 40960 B

    const int sp    = blockIdx.x >> 1;              // s-pair index 0..255
    const int dhalf = blockIdx.x & 1;
    const int s0    = sp * 2;
    const int tid   = threadIdx.x;
    const int lane  = tid & 63;
    const int wv    = tid >> 6;
    const int hi    = lane >> 5;
    const int d     = dhalf * 128 + wv * 32 + (lane & 31);

    // Stage all weight fragments to LDS: 10 chunks x 256 threads x 16 B = 40 KB.
#pragma unroll
    for (int c = 0; c < 10; ++c) {
        const char* g = (const char*)wsf + (size_t)(c * 256 + tid) * 16;
        char* lp = (char*)lds + (size_t)(c * 256 + wv * 64) * 16;
        __builtin_amdgcn_global_load_lds(
            (const __attribute__((address_space(1))) void*)g,
            (__attribute__((address_space(3))) void*)lp, 16, 0, 0);
    }

    // Two s-streams' x fragments (issue while staging is in flight):
    // lane holds x[q = 8*hi + j][s][d]  (B-operand of stage 1)
    const float* xp = x + s0 * DD + d + (hi ? 8 * SS * DD : 0);
    float xr0[8], xr1[8];
#pragma unroll
    for (int t = 0; t < 8; ++t) {
        xr0[t] = xp[t * SS * DD];
        xr1[t] = xp[t * SS * DD + DD];
    }
    B8 xb0, xb1;
#pragma unroll
    for (int t = 0; t < 4; ++t) {
        xb0.w[t] = packb(xr0[2 * t], xr0[2 * t + 1]);   // RNE (once per x value)
        xb1.w[t] = packb(xr1[2 * t], xr1[2 * t + 1]);
    }
    const bf16x8 xf0 = xb0.v, xf1 = xb1.v;

    __syncthreads();   // drains vmcnt (global_load_lds) per compiler semantics

    f32x16 a00{}, a10{}, a20{};   // stream 0 (s0):   ranks 0..2
    f32x16 a01{}, a11{}, a21{};   // stream 1 (s0+1): ranks 0..2
    const f32x16 zf{};

    const unsigned short* brl = lds + lane * 8;
    const unsigned short* crl = lds + BR_USH + lane * 8;

#pragma unroll 2
    for (int et = 0; et < 8; ++et) {
        const bf16x8 crA0 = *(const bf16x8*)(crl + (et * 2 + 0) * 512);
        const bf16x8 crA1 = *(const bf16x8*)(crl + (et * 2 + 1) * 512);
#pragma unroll
        for (int i = 0; i < NI; ++i) {
            const bf16x8 brA = *(const bf16x8*)(brl + (i * 8 + et) * 512);
            // two independent chains share one brA/crA read
            f32x16 g0 = __builtin_amdgcn_mfma_f32_32x32x16_bf16(brA, xf0, zf, 0, 0, 0);
            f32x16 g1 = __builtin_amdgcn_mfma_f32_32x32x16_bf16(brA, xf1, zf, 0, 0, 0);
            float p0[16], p1[16];
#pragma unroll
            for (int rr = 0; rr < 16; ++rr) {
                p0[rr] = __builtin_amdgcn_exp2f(g0[rr]);
                p1[rr] = __builtin_amdgcn_exp2f(g1[rr]);
            }
            B8 A0, B0, A1, B1;   // stage-2 B-operands for streams 0/1
#pragma unroll
            for (int rr = 0; rr < 4; ++rr) {
                A0.w[rr] = permpack(p0[2 * rr],     p0[2 * rr + 1]);
                B0.w[rr] = permpack(p0[2 * rr + 8], p0[2 * rr + 9]);
                A1.w[rr] = permpack(p1[2 * rr],     p1[2 * rr + 1]);
                B1.w[rr] = permpack(p1[2 * rr + 8], p1[2 * rr + 9]);
            }
            if (i == 0) {
                a00 = __builtin_amdgcn_mfma_f32_32x32x16_bf16(crA0, A0.v, a00, 0, 0, 0);
                a00 = __builtin_amdgcn_mfma_f32_32x32x16_bf16(crA1, B0.v, a00, 0, 0, 0);
                a01 = __builtin_amdgcn_mfma_f32_32x32x16_bf16(crA0, A1.v, a01, 0, 0, 0);
                a01 = __builtin_amdgcn_mfma_f32_32x32x16_bf16(crA1, B1.v, a01, 0, 0, 0);
            } else if (i == 1) {
                a10 = __builtin_amdgcn_mfma_f32_32x32x16_bf16(crA0, A0.v, a10, 0, 0, 0);
                a10 = __builtin_amdgcn_mfma_f32_32x32x16_bf16(crA1, B0.v, a10, 0, 0, 0);
                a11 = __builtin_amdgcn_mfma_f32_32x32x16_bf16(crA0, A1.v, a11, 0, 0, 0);
                a11 = __builtin_amdgcn_mfma_f32_32x32x16_bf16(crA1, B1.v, a11, 0, 0, 0);
            } else {
                a20 = __builtin_amdgcn_mfma_f32_32x32x16_bf16(crA0, A0.v, a20, 0, 0, 0);
                a20 = __builtin_amdgcn_mfma_f32_32x32x16_bf16(crA1, B0.v, a20, 0, 0, 0);
                a21 = __builtin_amdgcn_mfma_f32_32x32x16_bf16(crA0, A1.v, a21, 0, 0, 0);
                a21 = __builtin_amdgcn_mfma_f32_32x32x16_bf16(crA1, B1.v, a21, 0, 0, 0);
            }
        }
    }

    // l_i sits in C row 16 = reg 8 of hi=0 lanes; broadcast to hi=1 half
    float inv0[NI], inv1[NI];
#pragma unroll
    for (int i = 0; i < NI; ++i) {
        union { float f; unsigned u; } c0, c1;
        c0.f = (i == 0) ? a00[8] : (i == 1) ? a10[8] : a20[8];
        c1.f = (i == 0) ? a01[8] : (i == 1) ? a11[8] : a21[8];
        const uint2v r0 = __builtin_amdgcn_permlane32_swap(c0.u, c0.u, false, false);
        const uint2v r1 = __builtin_amdgcn_permlane32_swap(c1.u, c1.u, false, false);
        union { unsigned u; float f; } d0, d1;
        d0.u = r0.x; d1.u = r1.x;
        inv0[i] = 1.0f / d0.f;
        inv1[i] = 1.0f / d1.f;
    }

#pragma unroll
    for (int rr = 0; rr < 8; ++rr) {
        const int b = (rr & 3) + 8 * (rr >> 2) + 4 * hi;
        const float o0 = a00[rr] * inv0[0] + a10[rr] * inv0[1] + a20[rr] * inv0[2];
        const float o1 = a01[rr] * inv1[0] + a11[rr] * inv1[1] + a21[rr] * inv1[2];
        out[(b * SS + s0) * DD + d]     = o0;
        out[(b * SS + s0 + 1) * DD + d] = o1;
    }
}

extern "C" void kernel_launch(void* const* d_in, const int* in_sizes, int n_in,
                              void* d_out, int out_size, void* d_ws, size_t ws_size,
                              hipStream_t stream) {
    const float* x  = (const float*)d_in[0];
    const float* ar = (const float*)d_in[1];
    const float* br = (const float*)d_in[2];
    const float* cr = (const float*)d_in[3];
    float* out = (float*)d_out;

    unsigned short* wsf = (unsigned short*)d_ws;   // 40 KB: brf (24K) then crf (16K)

    hipLaunchKernelGGL(tt_prep, dim3(10), dim3(256), 0, stream, ar, br, cr, wsf);
    hipLaunchKernelGGL(tt_attn_mfma, dim3(SS), dim3(256), 0, stream, x, wsf, out);
}